// Round 6
// baseline (171.773 us; speedup 1.0000x reference)
//
#include <hip/hip_runtime.h>

#define DIN 1024
#define LSEQ 2048

typedef _Float16 f16;
typedef _Float16 half8 __attribute__((ext_vector_type(8)));
typedef float floatx4 __attribute__((ext_vector_type(4)));

__device__ __forceinline__ void async_ld16(const void* g, void* l) {
  __builtin_amdgcn_global_load_lds(
      (const __attribute__((address_space(1))) void*)g,
      (__attribute__((address_space(3))) void*)l, 16, 0, 0);
}

__device__ __forceinline__ float fast_exp2(float x) {
#if __has_builtin(__builtin_amdgcn_exp2f)
  return __builtin_amdgcn_exp2f(x);
#else
  return exp2f(x);
#endif
}

__device__ __forceinline__ unsigned int pack2_f16(float a, float b) {
#if __has_builtin(__builtin_amdgcn_cvt_pkrtz)
  typedef __fp16 fp16x2 __attribute__((ext_vector_type(2)));
  fp16x2 h = __builtin_amdgcn_cvt_pkrtz(a, b);
  return __builtin_bit_cast(unsigned int, h);
#else
  union { f16 h[2]; unsigned int u; } pk;
  pk.h[0] = (f16)a; pk.h[1] = (f16)b;
  return pk.u;
#endif
}

// ---------------- Kernel 1: W [k][n] fp32 -> Wt [n][k] fp16 ----------------
__global__ void __launch_bounds__(256) kwt(const float* __restrict__ wq,
                                           const float* __restrict__ wk,
                                           const float* __restrict__ wv,
                                           f16* __restrict__ wqt,
                                           f16* __restrict__ wkt,
                                           f16* __restrict__ wvt) {
  __shared__ float t[32][33];
  const float* src = blockIdx.z == 0 ? wq : (blockIdx.z == 1 ? wk : wv);
  f16* dst = blockIdx.z == 0 ? wqt : (blockIdx.z == 1 ? wkt : wvt);
  int k0 = blockIdx.x * 32, n0 = blockIdx.y * 32;
  int tx = threadIdx.x, ty = threadIdx.y;  // (32,8)
#pragma unroll
  for (int r = 0; r < 4; ++r)
    t[ty + r * 8][tx] = src[(k0 + ty + r * 8) * DIN + n0 + tx];
  __syncthreads();
#pragma unroll
  for (int r = 0; r < 4; ++r)
    dst[(n0 + ty + r * 8) * DIN + k0 + tx] = (f16)t[tx][ty + r * 8];
}

// ------------- Kernel 2: C = X(4096x1024) @ W -> Q/K/V fp16 ----------------
__global__ void __launch_bounds__(256) kproj(const float* __restrict__ xq,
                                             const float* __restrict__ xk,
                                             const f16* __restrict__ wqt,
                                             const f16* __restrict__ wkt,
                                             const f16* __restrict__ wvt,
                                             f16* __restrict__ qb,
                                             f16* __restrict__ kb,
                                             f16* __restrict__ vb) {
  __shared__ __align__(16) char As[128 * 128];
  __shared__ __align__(16) char Bs[128 * 128];
  const float* X;
  const f16* W;
  f16* dst;
  int z = blockIdx.z;
  if (z == 0) { X = xq; W = wqt; dst = qb; }
  else if (z == 1) { X = xk; W = wkt; dst = kb; }
  else { X = xk; W = wvt; dst = vb; }
  float oscale = (z == 0) ? 0.18033688011112042f : 1.0f;  // SC only for Q
  int m0 = blockIdx.y * 128, n0 = blockIdx.x * 128;
  int tid = threadIdx.x, lane = tid & 63, wid = tid >> 6;
  int wm = wid >> 1, wn = wid & 1;
  int c15 = lane & 15, g = lane >> 4;
  int l8 = lane >> 3, l7 = lane & 7;
  int kk = 8 * (l7 ^ l8);
  int swz = (c15 & 7) << 4;
  floatx4 acc[4][4] = {};

  for (int kt = 0; kt < 16; ++kt) {
    int k0 = kt * 64;
#pragma unroll
    for (int cc = 0; cc < 4; ++cc) {
      int c = wid * 4 + cc;
      async_ld16(&W[(n0 + c * 8 + l8) * DIN + k0 + kk], Bs + c * 1024);
    }
    {
      int q = tid & 15;
#pragma unroll
      for (int p = 0; p < 8; ++p) {
        int row = p * 16 + (tid >> 4);
        const float4 v = *(const float4*)&X[(m0 + row) * DIN + k0 + q * 4];
        union { unsigned int u[2]; uint2 v2; } pk;
        pk.u[0] = pack2_f16(v.x, v.y);
        pk.u[1] = pack2_f16(v.z, v.w);
        *(uint2*)(As + row * 128 + ((q * 8) ^ ((row & 7) << 4))) = pk.v2;
      }
    }
    __syncthreads();
#pragma unroll
    for (int ks = 0; ks < 2; ++ks) {
      int koff = (ks * 64 + g * 16) ^ swz;
      half8 af[4], bf[4];
#pragma unroll
      for (int i = 0; i < 4; ++i)
        af[i] = *(const half8*)(As + (wm * 64 + i * 16 + c15) * 128 + koff);
#pragma unroll
      for (int j = 0; j < 4; ++j)
        bf[j] = *(const half8*)(Bs + (wn * 64 + j * 16 + c15) * 128 + koff);
#pragma unroll
      for (int i = 0; i < 4; ++i)
#pragma unroll
        for (int j = 0; j < 4; ++j)
          acc[i][j] = __builtin_amdgcn_mfma_f32_16x16x32_f16(af[i], bf[j], acc[i][j], 0, 0, 0);
    }
    __syncthreads();
  }
#pragma unroll
  for (int i = 0; i < 4; ++i) {
    int mrow = m0 + wm * 64 + i * 16 + 4 * g;
#pragma unroll
    for (int j = 0; j < 4; ++j) {
      int n = n0 + wn * 64 + j * 16 + c15;
      int h = n >> 6, d = n & 63;
#pragma unroll
      for (int r = 0; r < 4; ++r) {
        int m = mrow + r;
        int b = m >> 11, lrow = m & 2047;
        dst[(((b << 4) + h) * 2048 + lrow) * 64 + d] = (f16)(acc[i][j][r] * oscale);
      }
    }
  }
}

// ------------- Kernel 3: V [bh][l][64] -> Vt [bh][64][l] fp16 --------------
__global__ void __launch_bounds__(256) kvt(const f16* __restrict__ vbuf,
                                           f16* __restrict__ vt) {
  __shared__ __align__(16) f16 t[64][72];
  int l0 = blockIdx.x * 64, bh = blockIdx.y;
  int tid = threadIdx.x;
  int lrow = tid >> 3, chunk = tid & 7;
#pragma unroll
  for (int p = 0; p < 2; ++p) {
    int l = p * 32 + lrow;
    *(uint4*)&t[l][chunk * 8] =
        *(const uint4*)&vbuf[(bh * 2048 + l0 + l) * 64 + chunk * 8];
  }
  __syncthreads();
#pragma unroll
  for (int p = 0; p < 2; ++p) {
    int d = p * 32 + lrow;
    union { f16 h[8]; uint4 u; } pk;
#pragma unroll
    for (int u = 0; u < 8; ++u) pk.h[u] = t[chunk * 8 + u][d];
    *(uint4*)&vt[(bh * 64 + d) * 2048 + l0 + chunk * 8] = pk.u;
  }
}

// --------------------- Kernel 4: flash attention ---------------------------
// kv-split waves: 64 q/block, KV tile 128, 4 waves each owning a 32-kv slice.
// Q (all 64 q) lives in registers per wave; each wave reads only ITS K rows
// and V kv-slice from LDS -> K/V LDS-read traffic /4 per kv. O and lsum are
// kv-partial per wave; cross-wave reduced once at the epilogue.
// Single K/V buffer; K restaged after BAR1, V after BAR2 (latency hidden
// behind the opposite compute phase). Shift-free exp2-domain softmax.
__global__ void __launch_bounds__(256, 3) kattn(const f16* __restrict__ qb,
                                                const f16* __restrict__ kbuf,
                                                const f16* __restrict__ vt,
                                                float* __restrict__ out) {
  // Ks [0,16384): [128 kv][128B] swz ((row&7)<<4)
  // Vs [16384,32768): [64 d][256B] swz ((d&15)<<4)
  // P  [32768,53248): per-wave 5120B strip = [64 q][80B]
  // ls [53248,54272): [4 w][4 j][16 c15] f32
  __shared__ __align__(16) char smem[54272];
  char* Ks = smem;
  char* Vs = smem + 16384;
  float* lsb = (float*)(smem + 53248);
  float* Obuf = (float*)smem;  // epilogue overlay [64 q][68 d] f32

  int id = blockIdx.x;
  int wi = id >> 3;
  int bh = ((id & 7) << 2) | (wi >> 5);  // 4 heads per XCD -> L2-resident K/V
  int q0 = (wi & 31) << 6;

  int tid = threadIdx.x, lane = tid & 63, w = tid >> 6;
  int c15 = lane & 15, g = lane >> 4;
  int l8 = lane >> 3, l7 = lane & 7;
  int kk = 8 * (l7 ^ l8);
  char* Pw = smem + 32768 + w * 5120;

  const f16* kbase = kbuf + (size_t)bh * 2048 * 64;
  const f16* vbase = vt + (size_t)bh * 64 * 2048;
  const f16* qbase = qb + ((size_t)bh * 2048 + q0) * 64;

  auto stageK = [&](int kv0) {  // wave w stages rows 32w..32w+31 (its own)
#pragma unroll
    for (int cc = 0; cc < 4; ++cc) {
      int c = w * 4 + cc;
      async_ld16(&kbase[(kv0 + c * 8 + l8) * 64 + kk], Ks + c * 1024);
    }
  };
  auto stageV = [&](int kv0) {  // [64 d][256B], swz ((d&15)<<4) via source
#pragma unroll
    for (int cc = 0; cc < 4; ++cc) {
      int c = w * 4 + cc;
      int dr = c * 4 + (lane >> 4);
      int kvo = 8 * ((lane & 15) ^ (4 * (c & 3) + (lane >> 4)));
      async_ld16(&vbase[(size_t)dr * 2048 + kv0 + kvo], Vs + c * 1024);
    }
  };

  // Q fragments straight from global: B-frag col q=16j+c15, k=ks*32+8g
  half8 qf[4][2];
#pragma unroll
  for (int j = 0; j < 4; ++j)
#pragma unroll
    for (int ks = 0; ks < 2; ++ks)
      qf[j][ks] = *(const half8*)&qbase[(16 * j + c15) * 64 + ks * 32 + 8 * g];

  stageK(0);
  stageV(0);
  __syncthreads();

  float ls[4] = {0.f, 0.f, 0.f, 0.f};
  floatx4 oacc[4][4] = {};  // [df][j], kv-partial for this wave

  for (int t = 0; t < 16; ++t) {
    // ---- QK: S^T[kv=32w+16i+4g+r][q=16j+c15], contraction k=64 ----
    floatx4 st[2][4] = {};
    __builtin_amdgcn_s_setprio(1);
#pragma unroll
    for (int ks = 0; ks < 2; ++ks)
#pragma unroll
      for (int i = 0; i < 2; ++i) {
        int row = 32 * w + 16 * i + c15;
        half8 kf = *(const half8*)(Ks + row * 128 +
                                   ((ks * 64 + 16 * g) ^ ((c15 & 7) << 4)));
#pragma unroll
        for (int j = 0; j < 4; ++j)
          st[i][j] = __builtin_amdgcn_mfma_f32_16x16x32_f16(kf, qf[j][ks], st[i][j], 0, 0, 0);
      }
    __builtin_amdgcn_s_setprio(0);
    __syncthreads();  // BAR1: all K reads done (also drains V(t) loads)
    if (t < 15) stageK((t + 1) * 128);  // in flight across softmax+PV

    // ---- shift-free softmax + P write (strip [64 q][80B], kv-local) ----
#pragma unroll
    for (int i = 0; i < 2; ++i)
#pragma unroll
      for (int j = 0; j < 4; ++j) {
        float p0 = fast_exp2(st[i][j][0]);
        float p1 = fast_exp2(st[i][j][1]);
        float p2 = fast_exp2(st[i][j][2]);
        float p3 = fast_exp2(st[i][j][3]);
        ls[j] += (p0 + p1) + (p2 + p3);
        union { unsigned int u[2]; uint2 v; } pk;
        pk.u[0] = pack2_f16(p0, p1);
        pk.u[1] = pack2_f16(p2, p3);
        *(uint2*)(Pw + (16 * j + c15) * 80 + 32 * i + 8 * g) = pk.v;
      }

    // ---- PV: O^T[d=16df+4g+r][q] += V^T[d][kv-slice] @ P^T ----
    half8 pf[4];
#pragma unroll
    for (int j = 0; j < 4; ++j)
      pf[j] = *(const half8*)(Pw + (16 * j + c15) * 80 + 16 * g);
    __builtin_amdgcn_s_setprio(1);
#pragma unroll
    for (int df = 0; df < 4; ++df) {
      int d = 16 * df + c15;
      half8 vf = *(const half8*)(Vs + d * 256 + ((64 * w + 16 * g) ^ (c15 << 4)));
#pragma unroll
      for (int j = 0; j < 4; ++j)
        oacc[df][j] = __builtin_amdgcn_mfma_f32_16x16x32_f16(vf, pf[j], oacc[df][j], 0, 0, 0);
    }
    __builtin_amdgcn_s_setprio(0);
    __syncthreads();  // BAR2: all V reads done (also drains K(t+1) loads)
    if (t < 15) stageV((t + 1) * 128);  // in flight across next QK
  }

  // ---- epilogue: reduce lsum and O across waves ----
#pragma unroll
  for (int j = 0; j < 4; ++j) {
    ls[j] += __shfl_xor(ls[j], 16, 64);
    ls[j] += __shfl_xor(ls[j], 32, 64);
  }
  if (g == 0) {
#pragma unroll
    for (int j = 0; j < 4; ++j) lsb[(w * 4 + j) * 16 + c15] = ls[j];
  }
  __syncthreads();

  for (int wp = 0; wp < 4; ++wp) {
    if (w == wp) {
#pragma unroll
      for (int df = 0; df < 4; ++df)
#pragma unroll
        for (int j = 0; j < 4; ++j) {
          float* dst = &Obuf[(16 * j + c15) * 68 + 16 * df + 4 * g];
          floatx4 v = oacc[df][j];
          if (wp > 0) v += *(floatx4*)dst;
          *(floatx4*)dst = v;
        }
    }
    __syncthreads();
  }

  // ---- normalize + store ----
  int b = bh >> 4, h = bh & 15;
  int row = tid >> 2, seg = tid & 3;
  int jj = row >> 4, cc = row & 15;
  float lst = lsb[(0 + jj) * 16 + cc] + lsb[(4 + jj) * 16 + cc] +
              lsb[(8 + jj) * 16 + cc] + lsb[(12 + jj) * 16 + cc];
  float inv = 1.f / lst;
  float* dstp = &out[((size_t)b * 2048 + q0 + row) * 1024 + h * 64 + seg * 16];
  const float* srcl = &Obuf[row * 68 + seg * 16];
#pragma unroll
  for (int u = 0; u < 4; ++u) {
    floatx4 v = *(const floatx4*)(srcl + u * 4) * inv;
    *(floatx4*)(dstp + u * 4) = v;
  }
}

// ---------------------------------------------------------------------------
extern "C" void kernel_launch(void* const* d_in, const int* in_sizes, int n_in,
                              void* d_out, int out_size, void* d_ws, size_t ws_size,
                              hipStream_t stream) {
  const float* xq = (const float*)d_in[0];
  const float* xk = (const float*)d_in[1];
  const float* wq = (const float*)d_in[2];
  const float* wk = (const float*)d_in[3];
  const float* wv = (const float*)d_in[4];
  char* ws = (char*)d_ws;
  f16* wqt = (f16*)(ws + (0ull << 20));
  f16* wkt = (f16*)(ws + (2ull << 20));
  f16* wvt = (f16*)(ws + (4ull << 20));
  f16* qbuf = (f16*)(ws + (6ull << 20));
  f16* kbuf = (f16*)(ws + (14ull << 20));
  f16* vbuf = (f16*)(ws + (22ull << 20));
  f16* vtb  = (f16*)(ws + (30ull << 20));

  kwt<<<dim3(32, 32, 3), dim3(32, 8), 0, stream>>>(wq, wk, wv, wqt, wkt, wvt);
  kproj<<<dim3(8, 32, 3), 256, 0, stream>>>(xq, xk, wqt, wkt, wvt, qbuf, kbuf, vbuf);
  kvt<<<dim3(32, 32), 256, 0, stream>>>(vbuf, vtb);
  kattn<<<1024, 256, 0, stream>>>(qbuf, kbuf, vtb, (float*)d_out);
}